// Round 2
// baseline (269.278 us; speedup 1.0000x reference)
//
#include <hip/hip_runtime.h>

#define BB   16
#define FIN  16
#define FOUT 16
#define HH   384
#define WW   384
#define LAT  512
#define NMIX 8
#define HW   (HH * WW)          // 147456
#define HW4  (HW / 4)           // 36864 float4 per channel plane
#define WSTRIDE 272             // per-sample ws floats: 256 kernel + 16 bias

typedef float f32x4 __attribute__((ext_vector_type(4)));

// ---------------------------------------------------------------------------
// Kernel A (tiny, 16 blocks): fold per-sample dynamic weights ONCE per sample.
//   mix[m]   = lat[b] . w_dyn[m] + b_dyn[m]
//   k[o][i]  = sum_m mix[m] * kernel_mix[m][o][i]   -> ws[b*272 + o*16+i]
//   bias[o]  = sum_m mix[m] * bias_mix[m][o]        -> ws[b*272 + 256+o]
// ---------------------------------------------------------------------------
__global__ __launch_bounds__(256)
void mixconv_weights(const float* __restrict__ lat,
                     const float* __restrict__ kernel_mix,   // [NMIX][FOUT][FIN]
                     const float* __restrict__ bias_mix,     // [NMIX][FOUT]
                     const float* __restrict__ w_dyn,        // [NMIX][LAT]
                     const float* __restrict__ b_dyn,        // [NMIX]
                     float* __restrict__ ws) {
    __shared__ float part[NMIX][32];
    __shared__ float mix_s[NMIX];
    const int t = threadIdx.x;
    const int b = blockIdx.x;

    {
        const int m = t & (NMIX - 1);       // 0..7
        const int c = t >> 3;               // 0..31, chunk of 16 elements
        const f32x4* lv = (const f32x4*)(lat + (size_t)b * LAT + c * 16);
        const f32x4* wv = (const f32x4*)(w_dyn + (size_t)m * LAT + c * 16);
        float acc = 0.f;
#pragma unroll
        for (int j = 0; j < 4; ++j) {
            f32x4 a = lv[j], w = wv[j];
            acc += a.x * w.x + a.y * w.y + a.z * w.z + a.w * w.w;
        }
        part[m][c] = acc;
    }
    __syncthreads();
    if (t < NMIX) {
        float s = 0.f;
#pragma unroll
        for (int c = 0; c < 32; ++c) s += part[t][c];
        mix_s[t] = s + b_dyn[t];
    }
    __syncthreads();

    float kacc = 0.f;
#pragma unroll
    for (int m = 0; m < NMIX; ++m)
        kacc += mix_s[m] * kernel_mix[m * FOUT * FIN + t];
    ws[b * WSTRIDE + t] = kacc;
    if (t < FOUT) {
        float bacc = 0.f;
#pragma unroll
        for (int m = 0; m < NMIX; ++m)
            bacc += mix_s[m] * bias_mix[m * FOUT + t];
        ws[b * WSTRIDE + 256 + t] = bacc;
    }
}

// ---------------------------------------------------------------------------
// Kernel B (streaming):
//   - PLAIN loads/stores (no nontemporal): exactly the memory path of the
//     measured 6.29 TB/s float4 copy and the 6.5 TB/s fills on this chip
//   - weights read via wave-uniform addresses -> scalar cache (s_load),
//     consumed as SGPR operands of v_fmac; NO LDS in this kernel at all
//   - barrier-free, one block = 256 float4 positions x all 16 channels
// ---------------------------------------------------------------------------
__global__ __launch_bounds__(256)
void mixconv_main(const float* __restrict__ x,
                  const float* __restrict__ wk,    // ws from kernel A
                  float* __restrict__ out) {
    const int t = threadIdx.x;
    const int b = blockIdx.y;

    const int p = blockIdx.x * 256 + t;     // float4 index in [0, HW4)
    const f32x4* xv = (const f32x4*)(x + (size_t)b * FIN * HW) + p;
    f32x4*       ov = (f32x4*)(out + (size_t)b * FOUT * HW) + p;

    // issue all 16 streaming loads up front (64 VGPRs, stays within 4 waves/SIMD)
    f32x4 xi[FIN];
#pragma unroll
    for (int i = 0; i < FIN; ++i)
        xi[i] = xv[(size_t)i * HW4];

    // wave-uniform weight base: compiler emits s_load_dwordx* through K$,
    // v_fma with SGPR source (1 SGPR operand per VALU instr is legal)
    const float* wb = wk + b * WSTRIDE;

#pragma unroll
    for (int o = 0; o < FOUT; ++o) {
        const float bo = wb[256 + o];
        f32x4 acc = {bo, bo, bo, bo};
#pragma unroll
        for (int i = 0; i < FIN; ++i)
            acc += wb[o * 16 + i] * xi[i];
        ov[(size_t)o * HW4] = acc;
    }
}

// ---------------------------------------------------------------------------
extern "C" void kernel_launch(void* const* d_in, const int* in_sizes, int n_in,
                              void* d_out, int out_size, void* d_ws, size_t ws_size,
                              hipStream_t stream) {
    const float* x          = (const float*)d_in[0];
    const float* lat        = (const float*)d_in[1];
    const float* kernel_mix = (const float*)d_in[2];
    const float* bias_mix   = (const float*)d_in[3];
    const float* w_dyn      = (const float*)d_in[4];
    const float* b_dyn      = (const float*)d_in[5];
    float* out = (float*)d_out;
    float* ws  = (float*)d_ws;      // needs 16*272*4 = 17408 B

    mixconv_weights<<<dim3(BB), dim3(256), 0, stream>>>(
        lat, kernel_mix, bias_mix, w_dyn, b_dyn, ws);

    dim3 grid(HW4 / 256, BB);               // (144, 16) = 2304 blocks
    mixconv_main<<<grid, dim3(256), 0, stream>>>(x, ws, out);
}

// Round 3
// 266.797 us; speedup vs baseline: 1.0093x; 1.0093x over previous
//
#include <hip/hip_runtime.h>

#define BB   16
#define FIN  16
#define FOUT 16
#define HH   384
#define WW   384
#define LAT  512
#define NMIX 8
#define HW   (HH * WW)          // 147456
#define HW4  (HW / 4)           // 36864 float4 per channel plane

typedef float f32x4 __attribute__((ext_vector_type(4)));

// ---------------------------------------------------------------------------
// Round-0 fused kernel (best measured: 254.8 us), ONE variable changed:
// LDS inflated to 72 KB -> 2 blocks/CU instead of ~4.
// Rationale: kernel B runs ~4.5 TB/s vs 6.3 copy ceiling; per-instruction
// coalescing is perfect, so the suspect is DRAM row thrash from ~16K
// concurrently-active 4KB regions (resident blocks x 16 planes). Halving
// resident blocks halves open regions; in-flight bytes (128 KB/CU) remain
// >> the ~9.2 KB needed to saturate HBM at ~900cy latency.
// ---------------------------------------------------------------------------
__global__ __launch_bounds__(256)
void mixconv_fused(const float* __restrict__ x,
                   const float* __restrict__ lat,
                   const float* __restrict__ kernel_mix,   // [NMIX][FOUT][FIN]
                   const float* __restrict__ bias_mix,     // [NMIX][FOUT]
                   const float* __restrict__ w_dyn,        // [NMIX][LAT]
                   const float* __restrict__ b_dyn,        // [NMIX]
                   float* __restrict__ out) {
    // 72 KB LDS occupancy throttle; live weight arrays aliased into it.
    __shared__ float big[18432];
    float (*part)[32]  = (float (*)[32])&big[0];      // [NMIX][32]
    float* mix_s       = &big[256];                   // [NMIX]
    float (*ksh)[FIN]  = (float (*)[FIN])&big[264];   // [FOUT][FIN]
    float* bsh         = &big[520];                   // [FOUT]

    const int t = threadIdx.x;
    const int b = blockIdx.y;

    // ---- phase 0: issue streaming x loads first ---------------------------
    const int p = blockIdx.x * 256 + t;     // float4 index in [0, HW4)
    const f32x4* xv = (const f32x4*)(x + (size_t)b * FIN * HW) + p;
    f32x4*       ov = (f32x4*)(out + (size_t)b * FOUT * HW) + p;

    f32x4 xi[FIN];
#pragma unroll
    for (int i = 0; i < FIN; ++i)
        xi[i] = __builtin_nontemporal_load(xv + (size_t)i * HW4);

    // ---- phase 1: mix[m] = lat[b] . w_dyn[m] + b_dyn[m] -------------------
    {
        const int m = t & (NMIX - 1);       // 0..7
        const int c = t >> 3;               // 0..31, chunk of 16 elements
        const f32x4* lv = (const f32x4*)(lat + (size_t)b * LAT + c * 16);
        const f32x4* wv = (const f32x4*)(w_dyn + (size_t)m * LAT + c * 16);
        float acc = 0.f;
#pragma unroll
        for (int j = 0; j < 4; ++j) {
            f32x4 a = lv[j], w = wv[j];
            acc += a.x * w.x + a.y * w.y + a.z * w.z + a.w * w.w;
        }
        part[m][c] = acc;
    }
    __syncthreads();
    if (t < NMIX) {
        float s = 0.f;
#pragma unroll
        for (int c = 0; c < 32; ++c) s += part[t][c];
        mix_s[t] = s + b_dyn[t];
    }
    __syncthreads();

    // ---- phase 2: fold per-sample weights into LDS -------------------------
    {
        float kacc = 0.f;
#pragma unroll
        for (int m = 0; m < NMIX; ++m)
            kacc += mix_s[m] * kernel_mix[m * FOUT * FIN + t];
        ((float*)ksh)[t] = kacc;
        if (t < FOUT) {
            float bacc = 0.f;
#pragma unroll
            for (int m = 0; m < NMIX; ++m)
                bacc += mix_s[m] * bias_mix[m * FOUT + t];
            bsh[t] = bacc;
        }
    }
    __syncthreads();

    // ---- phase 3: consume x, matvec, stream out ---------------------------
#pragma unroll
    for (int o = 0; o < FOUT; ++o) {
        const f32x4 k0 = *(const f32x4*)&ksh[o][0];
        const f32x4 k1 = *(const f32x4*)&ksh[o][4];
        const f32x4 k2 = *(const f32x4*)&ksh[o][8];
        const f32x4 k3 = *(const f32x4*)&ksh[o][12];
        const float bo = bsh[o];
        f32x4 acc = {bo, bo, bo, bo};
        acc += k0.x * xi[0];  acc += k0.y * xi[1];
        acc += k0.z * xi[2];  acc += k0.w * xi[3];
        acc += k1.x * xi[4];  acc += k1.y * xi[5];
        acc += k1.z * xi[6];  acc += k1.w * xi[7];
        acc += k2.x * xi[8];  acc += k2.y * xi[9];
        acc += k2.z * xi[10]; acc += k2.w * xi[11];
        acc += k3.x * xi[12]; acc += k3.y * xi[13];
        acc += k3.z * xi[14]; acc += k3.w * xi[15];
        __builtin_nontemporal_store(acc, ov + (size_t)o * HW4);
    }
}

// ---------------------------------------------------------------------------
extern "C" void kernel_launch(void* const* d_in, const int* in_sizes, int n_in,
                              void* d_out, int out_size, void* d_ws, size_t ws_size,
                              hipStream_t stream) {
    const float* x          = (const float*)d_in[0];
    const float* lat        = (const float*)d_in[1];
    const float* kernel_mix = (const float*)d_in[2];
    const float* bias_mix   = (const float*)d_in[3];
    const float* w_dyn      = (const float*)d_in[4];
    const float* b_dyn      = (const float*)d_in[5];
    float* out = (float*)d_out;

    dim3 grid(HW4 / 256, BB);               // (144, 16) = 2304 blocks
    mixconv_fused<<<grid, dim3(256), 0, stream>>>(
        x, lat, kernel_mix, bias_mix, w_dyn, b_dyn, out);
}

// Round 4
// 256.146 us; speedup vs baseline: 1.0513x; 1.0416x over previous
//
#include <hip/hip_runtime.h>

#define BB   16
#define FIN  16
#define FOUT 16
#define HH   384
#define WW   384
#define LAT  512
#define NMIX 8
#define HW   (HH * WW)          // 147456
#define HW4  (HW / 4)           // 36864 float4 per channel plane

typedef float f32x4 __attribute__((ext_vector_type(4)));

// ---------------------------------------------------------------------------
// Round-0 fused kernel (best measured: 254.8 us), ONE variable changed:
// output stores are PLAIN (cacheable) instead of nontemporal.
// Rationale: the rocclr poison fills -- plain full-line stores -- sustain
// 6.6-6.8 TB/s, the fastest write path observed on this chip; our nt stores
// are the only write-side difference. r2 bundled plain-loads+plain-stores+
// sgpr-weights and regressed, which bounds the SUM, not the store term.
// Loads stay nontemporal (no reuse; avoid L2 churn). Weights stay in LDS.
// ---------------------------------------------------------------------------
__global__ __launch_bounds__(256)
void mixconv_fused(const float* __restrict__ x,
                   const float* __restrict__ lat,
                   const float* __restrict__ kernel_mix,   // [NMIX][FOUT][FIN]
                   const float* __restrict__ bias_mix,     // [NMIX][FOUT]
                   const float* __restrict__ w_dyn,        // [NMIX][LAT]
                   const float* __restrict__ b_dyn,        // [NMIX]
                   float* __restrict__ out) {
    __shared__ float part[NMIX][32];
    __shared__ float mix_s[NMIX];
    __shared__ float ksh[FOUT][FIN];
    __shared__ float bsh[FOUT];

    const int t = threadIdx.x;
    const int b = blockIdx.y;

    // ---- phase 0: issue streaming x loads first ---------------------------
    const int p = blockIdx.x * 256 + t;     // float4 index in [0, HW4)
    const f32x4* xv = (const f32x4*)(x + (size_t)b * FIN * HW) + p;
    f32x4*       ov = (f32x4*)(out + (size_t)b * FOUT * HW) + p;

    f32x4 xi[FIN];
#pragma unroll
    for (int i = 0; i < FIN; ++i)
        xi[i] = __builtin_nontemporal_load(xv + (size_t)i * HW4);

    // ---- phase 1: mix[m] = lat[b] . w_dyn[m] + b_dyn[m] -------------------
    {
        const int m = t & (NMIX - 1);       // 0..7
        const int c = t >> 3;               // 0..31, chunk of 16 elements
        const f32x4* lv = (const f32x4*)(lat + (size_t)b * LAT + c * 16);
        const f32x4* wv = (const f32x4*)(w_dyn + (size_t)m * LAT + c * 16);
        float acc = 0.f;
#pragma unroll
        for (int j = 0; j < 4; ++j) {
            f32x4 a = lv[j], w = wv[j];
            acc += a.x * w.x + a.y * w.y + a.z * w.z + a.w * w.w;
        }
        part[m][c] = acc;
    }
    __syncthreads();
    if (t < NMIX) {
        float s = 0.f;
#pragma unroll
        for (int c = 0; c < 32; ++c) s += part[t][c];
        mix_s[t] = s + b_dyn[t];
    }
    __syncthreads();

    // ---- phase 2: fold per-sample weights into LDS -------------------------
    {
        float kacc = 0.f;
#pragma unroll
        for (int m = 0; m < NMIX; ++m)
            kacc += mix_s[m] * kernel_mix[m * FOUT * FIN + t];
        ((float*)ksh)[t] = kacc;
        if (t < FOUT) {
            float bacc = 0.f;
#pragma unroll
            for (int m = 0; m < NMIX; ++m)
                bacc += mix_s[m] * bias_mix[m * FOUT + t];
            bsh[t] = bacc;
        }
    }
    __syncthreads();

    // ---- phase 3: consume x, matvec, PLAIN stores -------------------------
#pragma unroll
    for (int o = 0; o < FOUT; ++o) {
        const f32x4 k0 = *(const f32x4*)&ksh[o][0];
        const f32x4 k1 = *(const f32x4*)&ksh[o][4];
        const f32x4 k2 = *(const f32x4*)&ksh[o][8];
        const f32x4 k3 = *(const f32x4*)&ksh[o][12];
        const float bo = bsh[o];
        f32x4 acc = {bo, bo, bo, bo};
        acc += k0.x * xi[0];  acc += k0.y * xi[1];
        acc += k0.z * xi[2];  acc += k0.w * xi[3];
        acc += k1.x * xi[4];  acc += k1.y * xi[5];
        acc += k1.z * xi[6];  acc += k1.w * xi[7];
        acc += k2.x * xi[8];  acc += k2.y * xi[9];
        acc += k2.z * xi[10]; acc += k2.w * xi[11];
        acc += k3.x * xi[12]; acc += k3.y * xi[13];
        acc += k3.z * xi[14]; acc += k3.w * xi[15];
        ov[(size_t)o * HW4] = acc;          // plain store: the fill's 6.6 TB/s path
    }
}

// ---------------------------------------------------------------------------
extern "C" void kernel_launch(void* const* d_in, const int* in_sizes, int n_in,
                              void* d_out, int out_size, void* d_ws, size_t ws_size,
                              hipStream_t stream) {
    const float* x          = (const float*)d_in[0];
    const float* lat        = (const float*)d_in[1];
    const float* kernel_mix = (const float*)d_in[2];
    const float* bias_mix   = (const float*)d_in[3];
    const float* w_dyn      = (const float*)d_in[4];
    const float* b_dyn      = (const float*)d_in[5];
    float* out = (float*)d_out;

    dim3 grid(HW4 / 256, BB);               // (144, 16) = 2304 blocks
    mixconv_fused<<<grid, dim3(256), 0, stream>>>(
        x, lat, kernel_mix, bias_mix, w_dyn, b_dyn, out);
}